// Round 15
// baseline (905.858 us; speedup 1.0000x reference)
//
#include <hip/hip_runtime.h>
#include <cstdio>

// MoE top-2 FFN: B=4,S=2048,D=1024 -> T=8192 tokens; E=8, H=4096, K_TOP=2.
// Round 15: kill the DRAM-row-thrash transpose wall (3 impls stuck at 287us /
// 1TB/s: one global side was always <=256B-granular at 2-16KB stride). New:
// TILED weight layout Wt[e][k8][n][8k] (16B granules). Prep reads 8 full
// 16KB k-rows contiguously, LDS-transposes, writes 16-64KB contiguous slabs
// — both DRAM sides friendly. GEMM consumes it by changing ONLY the B-source
// granule address (LDS image bit-identical to r12/r13's validated path).
// GEMM/A-side/swizzle/supertile/epilogues verbatim from r13 (813us, passed).

#define T_TOK 8192
#define DIM   1024
#define NEXP  8
#define HID   4096
#define MAXR  18432  // 16384 rows + 8 experts * up-to-255 pad, rounded to 256

typedef float          f32x4   __attribute__((ext_vector_type(4)));
typedef short          bf16x8  __attribute__((ext_vector_type(8)));
typedef unsigned short u16x8   __attribute__((ext_vector_type(8)));
typedef unsigned short u16x4   __attribute__((ext_vector_type(4)));

static __device__ __forceinline__ unsigned short f2bf(float f) {
  unsigned int u = __builtin_bit_cast(unsigned int, f);
  u = (u + 0x7FFFu + ((u >> 16) & 1u)) >> 16;   // round-nearest-even (finite inputs)
  return (unsigned short)u;
}

// async global->LDS, 16B per lane; LDS dest = wave-uniform base + lane*16
static __device__ __forceinline__ void gl16(const void* g, void* l) {
  __builtin_amdgcn_global_load_lds(
      (const __attribute__((address_space(1))) unsigned int*)g,
      (__attribute__((address_space(3))) unsigned int*)l,
      16, 0, 0);
}

// ---------------- tiled transpose-convert ------------------------------------
// W[e][K][N] fp32 -> Wt granules [e][k8][n][8] bf16 (granule = 8 k-consecutive
// values of one column n, 16B).  Block = (e, k8): slab of 8 k-rows x N cols.
// Phase A: contiguous row reads (16KB/row), convert, LDS [8][N-chunk].
// Phase B: LDS column gather (8x u16), pack u16x8, CONTIGUOUS granule writes
// (wave writes 4KB runs).  All scatter confined to LDS.
__global__ __launch_bounds__(256) void tile_k(const float* __restrict__ W1,
                                              const float* __restrict__ W2,
                                              unsigned short* __restrict__ T1,
                                              unsigned short* __restrict__ T2) {
  __shared__ unsigned short sl[8 * 1028];        // stride 1028 shorts: 8B-aligned rows,
                                                 // column banks spread (2k + n/2)
  int id = blockIdx.x;
  const float* W; unsigned short* T; int K, N, blk;
  if (id < 1024) { W = W1; T = T1; K = DIM; N = HID; blk = id; }          // 8e x 128 k8
  else           { W = W2; T = T2; K = HID; N = DIM; blk = id - 1024; }   // 8e x 512 k8
  int kpb = K / 8;
  int e = blk / kpb, k8 = blk % kpb;
  const float* src = W + (size_t)e * K * N + (size_t)k8 * 8 * N;
  unsigned short* dst = T + (size_t)e * K * N + (size_t)k8 * 8 * N;
  int t = threadIdx.x;
  int kr = t >> 5, f4 = (t & 31) * 4;            // row 0..7, col base (x4 floats)
  int nchunk = N / 1024;
  for (int c = 0; c < nchunk; ++c) {
    if (c) __syncthreads();                      // prev chunk fully consumed
#pragma unroll
    for (int u = 0; u < 8; ++u) {
      int col = f4 + u * 128;
      float4 v = *(const float4*)(src + (size_t)kr * N + c * 1024 + col);
      u16x4 o;
      o[0] = f2bf(v.x); o[1] = f2bf(v.y); o[2] = f2bf(v.z); o[3] = f2bf(v.w);
      *(u16x4*)(sl + kr * 1028 + col) = o;
    }
    __syncthreads();
#pragma unroll
    for (int j = 0; j < 4; ++j) {
      int n = t * 4 + j;
      u16x8 o;
#pragma unroll
      for (int k = 0; k < 8; ++k) o[k] = sl[k * 1028 + n];
      *(u16x8*)(dst + ((size_t)c * 1024 + n) * 8) = o;
    }
  }
}

// ---------------- router (standalone, grid = T/4) ----------------------------
__global__ __launch_bounds__(256) void router_k(const float* __restrict__ x,
                                                const float* __restrict__ Wr,
                                                const float* __restrict__ br,
                                                int* __restrict__ meta,
                                                int2* __restrict__ top_i,
                                                float2* __restrict__ top_w) {
  int lane = threadIdx.x & 63;
  int wid  = threadIdx.x >> 6;
  int t = blockIdx.x * 4 + wid;
  const float* xp = x + (size_t)t * DIM + lane * 16;
  float acc[NEXP];
#pragma unroll
  for (int e = 0; e < NEXP; ++e) acc[e] = 0.f;
#pragma unroll
  for (int j = 0; j < 16; j += 4) {
    float4 xv = *(const float4*)(xp + j);
    const float* wp = Wr + (size_t)(lane * 16 + j) * NEXP;
#pragma unroll
    for (int jj = 0; jj < 4; ++jj) {
      float xs = jj == 0 ? xv.x : jj == 1 ? xv.y : jj == 2 ? xv.z : xv.w;
      float4 w0 = *(const float4*)(wp + jj * NEXP);
      float4 w1 = *(const float4*)(wp + jj * NEXP + 4);
      acc[0] += xs * w0.x; acc[1] += xs * w0.y; acc[2] += xs * w0.z; acc[3] += xs * w0.w;
      acc[4] += xs * w1.x; acc[5] += xs * w1.y; acc[6] += xs * w1.z; acc[7] += xs * w1.w;
    }
  }
#pragma unroll
  for (int off = 32; off > 0; off >>= 1) {
#pragma unroll
    for (int e = 0; e < NEXP; ++e) acc[e] += __shfl_xor(acc[e], off);
  }
  if (lane == 0) {
    float l[NEXP];
#pragma unroll
    for (int e = 0; e < NEXP; ++e) l[e] = acc[e] + br[e];
    int e1 = 0;
#pragma unroll
    for (int e = 1; e < NEXP; ++e) if (l[e] > l[e1]) e1 = e;      // ties -> lower idx
    int e2 = (e1 == 0) ? 1 : 0;
#pragma unroll
    for (int e = 0; e < NEXP; ++e) if (e != e1 && l[e] > l[e2]) e2 = e;
    float g  = expf(l[e2] - l[e1]);              // softmax over top-2 == renorm of full softmax
    float w1 = 1.f / (1.f + g);
    top_i[t] = make_int2(e1, e2);
    top_w[t] = make_float2(w1, 1.f - w1);
    atomicAdd(&meta[e1], 1);
    atomicAdd(&meta[e2], 1);
  }
}

// -------- fill: default row arrays (pad rows: token 0, weight 0) -------------
__global__ __launch_bounds__(256) void fill_k(int* __restrict__ tok_of_row,
                                              float* __restrict__ wt_of_row) {
  int i = blockIdx.x * 256 + threadIdx.x;
  if (i < MAXR) { tok_of_row[i] = 0; wt_of_row[i] = 0.f; }
}

// -------- prefix: padded (x256) offsets ------------------------------------
__global__ void prefix_k(int* __restrict__ meta) {
  if (threadIdx.x == 0) {
    int s = 0;
#pragma unroll
    for (int e = 0; e < NEXP; ++e) {
      meta[16 + e] = s;                          // poff[e]
      s += (meta[e] + 255) & ~255;
    }
    meta[24] = s;                                // poff[8]
    meta[25] = s;                                // total_padded (<= MAXR always)
  }
}

// ---------------- scatter: token -> packed expert row ------------------------
__global__ __launch_bounds__(256) void scatter_k(const int2* __restrict__ top_i,
                                                 const float2* __restrict__ top_w,
                                                 int* __restrict__ meta,
                                                 int* __restrict__ row_of,
                                                 int* __restrict__ tok_of_row,
                                                 float* __restrict__ wt_of_row) {
  int t = blockIdx.x * 256 + threadIdx.x;
  int2  ei = top_i[t];
  float2 w = top_w[t];
  int p = atomicAdd(&meta[8 + ei.x], 1);
  int r = meta[16 + ei.x] + p;
  tok_of_row[r] = t; wt_of_row[r] = w.x; row_of[t * 2] = r;
  p = atomicAdd(&meta[8 + ei.y], 1);
  r = meta[16 + ei.y] + p;
  tok_of_row[r] = t; wt_of_row[r] = w.y; row_of[t * 2 + 1] = r;
}

// ---------------- gather: xg[r][:] = bf16(x[tok[r]][:]) ----------------------
__global__ __launch_bounds__(256) void gather_k(const float* __restrict__ x,
                                                const int* __restrict__ tok_of_row,
                                                const int* __restrict__ meta,
                                                unsigned short* __restrict__ xg) {
  int r = blockIdx.x;
  if (r >= meta[25]) return;
  int t = tok_of_row[r];
  int c = threadIdx.x * 4;
  float4 v = *(const float4*)(x + (size_t)t * DIM + c);
  u16x4 o;
  o[0] = f2bf(v.x); o[1] = f2bf(v.y); o[2] = f2bf(v.z); o[3] = f2bf(v.w);
  *(u16x4*)(xg + (size_t)r * DIM + c) = o;
}

// ---------------- grouped GEMM: r13 loop, B from TILED layout ----------------
// A: [M][KTOT] bf16 packed rows.  Wt: [E][KTOT/8][NTOT][8] bf16 granules.
// Identical LDS image / swizzle / fragments / epilogue to r12/r13 (validated);
// only the B-staging SOURCE address changed: granule (k8 = kt*8+s, n).
// 128x128 tile, BK=64, 4 waves, 32KB LDS, XCD-chunked 4x4 supertiles, pad-skip.
// EPI 0: h = bf16(gelu(acc+b1))   EPI 1: atomicAdd out[tok] += (acc+b2)*wt

template <int KTOT, int NTOT, int EPI>
__global__ __launch_bounds__(256, 4) void gemmv15_k(const unsigned short* __restrict__ A,
                                                    const unsigned short* __restrict__ Wt,
                                                    const float* __restrict__ bias,
                                                    const int* __restrict__ meta,
                                                    const float* __restrict__ wt_of_row,
                                                    const int* __restrict__ tok_of_row,
                                                    void* __restrict__ Cout) {
  constexpr int NN  = NTOT / 128;                // 32 or 8
  constexpr int NXB = MAXR / 128;                // 144 row tiles
  constexpr int NWG = NXB * NN;                  // 4608 or 1152, both % 8 == 0
  constexpr int NSR = NXB / 4;                   // 36 row supertiles
  constexpr int NKT = KTOT / 64;                 // 16 or 64
  __shared__ __align__(16) unsigned short lds[16384];   // 32 KiB

  int id = ((int)blockIdx.x & 7) * (NWG / 8) + ((int)blockIdx.x >> 3);
  int sid = id >> 4, sub = id & 15;
  int row0 = ((sid % NSR) * 4 + (sub & 3)) * 128;
  int n0   = ((sid / NSR) * 4 + (sub >> 2)) * 128;
  if (row0 >= meta[25]) return;                  // beyond padded total (block-uniform)
  int e = 0;
  while (meta[17 + e] <= row0) ++e;              // tiles never straddle experts
  if (row0 - meta[16 + e] >= meta[e]) return;    // all-pad tile: skip (wt==0 gates EPI1)
  const unsigned short* Wp = Wt + (size_t)e * (size_t)KTOT * NTOT;

  int tid = threadIdx.x;
  int lane = tid & 63, wid = tid >> 6;
  int wm = wid >> 1, wn = wid & 1;               // 2x2 waves, each owns 64x64 of C

  // staging (T2 write side): source col-slot s = (tid&7) ^ ((tid>>3)&7)
  int s = (tid & 7) ^ ((tid >> 3) & 7);
  const unsigned short* pA = A + (size_t)(row0 + (tid >> 3)) * KTOT + s * 8;
  // B source: tiled granule (k8 = kt*8 + s, n = n0 + 32i + (tid>>3))
  const unsigned short* pB = Wp + ((size_t)s * NTOT + n0 + (tid >> 3)) * 8;

  // fragment reads (T2 read side): slot = (kk*4+g) ^ (am&7)
  int am = lane & 15, g = lane >> 4;
  int sw0 = ((0 * 4 + g) ^ (am & 7)) * 8;
  int sw1 = ((1 * 4 + g) ^ (am & 7)) * 8;
  int aRow = (wm * 64 + am) * 64;                // + i*1024 per fragment
  int bRow = 8192 + (wn * 64 + am) * 64;         // + j*1024 per fragment

  f32x4 acc[4][4];
#pragma unroll
  for (int i = 0; i < 4; ++i)
#pragma unroll
    for (int j = 0; j < 4; ++j) acc[i][j] = (f32x4){0.f, 0.f, 0.f, 0.f};

  for (int kt = 0; kt < NKT; ++kt) {
    __syncthreads();                             // prev compute done before overwrite
#pragma unroll
    for (int i = 0; i < 4; ++i) {
      gl16(pA + (size_t)(i * 32) * KTOT + kt * 64, lds + i * 2048 + tid * 8);
      gl16(pB + (size_t)(i * 32) * 8 + (size_t)kt * 64 * NTOT,
           lds + 8192 + i * 2048 + tid * 8);
    }
    __syncthreads();                             // compiler drains vmcnt before barrier
#pragma unroll
    for (int kk = 0; kk < 2; ++kk) {
      int sw = kk ? sw1 : sw0;
      bf16x8 af[4], bv[4];
#pragma unroll
      for (int i = 0; i < 4; ++i)
        af[i] = *(const bf16x8*)(lds + aRow + i * 1024 + sw);
#pragma unroll
      for (int j = 0; j < 4; ++j)
        bv[j] = *(const bf16x8*)(lds + bRow + j * 1024 + sw);
#pragma unroll
      for (int i = 0; i < 4; ++i)
#pragma unroll
        for (int j = 0; j < 4; ++j)
          acc[i][j] = __builtin_amdgcn_mfma_f32_16x16x32_bf16(af[i], bv[j], acc[i][j], 0, 0, 0);
    }
  }

  // epilogue.  C/D: col n = lane&15, row m = (lane>>4)*4 + reg  (validated)
  int rbase = row0 + wm * 64 + (g << 2);
  int nbase = n0 + wn * 64 + am;
  if constexpr (EPI == 0) {
    unsigned short* Hp = (unsigned short*)Cout;
    const float* bp = bias + (size_t)e * NTOT;
#pragma unroll
    for (int i = 0; i < 4; ++i)
#pragma unroll
      for (int j = 0; j < 4; ++j) {
        int n = nbase + j * 16;
        float bv = bp[n];
#pragma unroll
        for (int gg = 0; gg < 4; ++gg) {
          int m = rbase + i * 16 + gg;
          float v = acc[i][j][gg] + bv;
          v = 0.5f * v * (1.f + erff(v * 0.70710678118654752f));   // exact gelu
          Hp[(size_t)m * NTOT + n] = f2bf(v);
        }
      }
  } else {
    float* Op = (float*)Cout;
    const float* bp = bias + (size_t)e * NTOT;
#pragma unroll
    for (int i = 0; i < 4; ++i)
#pragma unroll
      for (int gg = 0; gg < 4; ++gg) {
        int m = rbase + i * 16 + gg;
        float wt = wt_of_row[m];
        if (wt != 0.f) {                         // pad rows excluded (wt exactly 0)
          float* orow = Op + (size_t)tok_of_row[m] * DIM;
#pragma unroll
          for (int j = 0; j < 4; ++j) {
            int n = nbase + j * 16;
            atomicAdd(orow + n, (acc[i][j][gg] + bp[n]) * wt);
          }
        }
      }
  }
}

extern "C" void kernel_launch(void* const* d_in, const int* in_sizes, int n_in,
                              void* d_out, int out_size, void* d_ws, size_t ws_size,
                              hipStream_t stream) {
  const float* x  = (const float*)d_in[0];
  const float* Wr = (const float*)d_in[1];
  const float* br = (const float*)d_in[2];
  const float* W1 = (const float*)d_in[3];
  const float* b1 = (const float*)d_in[4];
  const float* W2 = (const float*)d_in[5];
  const float* b2 = (const float*)d_in[6];
  float* out = (float*)d_out;

  char* base = (char*)d_ws;
  size_t off = 0;
  auto carve = [&](size_t bytes) -> void* {
    void* r = base + off;
    off = (off + bytes + 255) & ~(size_t)255;
    return r;
  };
  int*            meta       = (int*)carve(26 * 4);
  int2*           top_i      = (int2*)carve((size_t)T_TOK * 8);
  float2*         top_w      = (float2*)carve((size_t)T_TOK * 8);
  int*            row_of     = (int*)carve((size_t)T_TOK * 2 * 4);
  int*            tok_of_row = (int*)carve((size_t)MAXR * 4);
  float*          wt_of_row  = (float*)carve((size_t)MAXR * 4);
  unsigned short* xg         = (unsigned short*)carve((size_t)MAXR * DIM * 2);
  unsigned short* W1t        = (unsigned short*)carve((size_t)NEXP * DIM * HID * 2);
  unsigned short* W2t        = (unsigned short*)carve((size_t)NEXP * DIM * HID * 2);
  unsigned short* hbuf       = (unsigned short*)carve((size_t)MAXR * HID * 2);
  if (off > ws_size) {
    fprintf(stderr, "kernel_launch: ws_size too small: need %zu have %zu\n", off, ws_size);
    return;
  }

  hipMemsetAsync(meta, 0, 26 * 4, stream);
  hipMemsetAsync(out, 0, (size_t)out_size * 4, stream);   // GEMM2 atomicAdds into out
  hipLaunchKernelGGL(tile_k, dim3(1024 + 4096), dim3(256), 0, stream, W1, W2, W1t, W2t);
  hipLaunchKernelGGL(router_k, dim3(T_TOK / 4), dim3(256), 0, stream,
                     x, Wr, br, meta, top_i, top_w);
  hipLaunchKernelGGL(fill_k, dim3(MAXR / 256), dim3(256), 0, stream,
                     tok_of_row, wt_of_row);
  hipLaunchKernelGGL(prefix_k, dim3(1), dim3(64), 0, stream, meta);
  hipLaunchKernelGGL(scatter_k, dim3(T_TOK / 256), dim3(256), 0, stream,
                     top_i, top_w, meta, row_of, tok_of_row, wt_of_row);
  hipLaunchKernelGGL(gather_k, dim3(MAXR), dim3(256), 0, stream, x, tok_of_row, meta, xg);
  hipLaunchKernelGGL((gemmv15_k<DIM, HID, 0>), dim3((MAXR / 128) * (HID / 128)), dim3(256), 0,
                     stream, xg, W1t, b1, meta, wt_of_row, tok_of_row, (void*)hbuf);
  hipLaunchKernelGGL((gemmv15_k<HID, DIM, 1>), dim3((MAXR / 128) * (DIM / 128)), dim3(256), 0,
                     stream, hbuf, W2t, b2, meta, wt_of_row, tok_of_row, (void*)out);
}

// Round 16
// 801.786 us; speedup vs baseline: 1.1298x; 1.1298x over previous
//
#include <hip/hip_runtime.h>
#include <cstdio>

// MoE top-2 FFN: B=4,S=2048,D=1024 -> T=8192 tokens; E=8, H=4096, K_TOP=2.
// Round 16: r13 config (best measured, 813us) + gather elimination:
// x converted once to bf16 xb[T][D] (streamed, folded into prep_k);
// GEMM1 A-staging reads token rows DIRECTLY via per-lane gl16 source
// addresses from tok_of_row (4 statically-unrolled row pointers).
// gather_k and the xg buffer are gone. Everything else r13-verbatim:
// LDS-staged transpose prep, BK=64+swizzle GEMM, 4x4 supertile grid,
// pad-tile skip, atomic GEMM2 epilogue.

#define T_TOK 8192
#define DIM   1024
#define NEXP  8
#define HID   4096
#define MAXR  18432  // 16384 rows + 8 experts * up-to-255 pad, rounded to 256

typedef float          f32x4   __attribute__((ext_vector_type(4)));
typedef short          bf16x8  __attribute__((ext_vector_type(8)));
typedef unsigned short u16x8   __attribute__((ext_vector_type(8)));
typedef unsigned short u16x4   __attribute__((ext_vector_type(4)));

static __device__ __forceinline__ unsigned short f2bf(float f) {
  unsigned int u = __builtin_bit_cast(unsigned int, f);
  u = (u + 0x7FFFu + ((u >> 16) & 1u)) >> 16;   // round-nearest-even (finite inputs)
  return (unsigned short)u;
}

// async global->LDS, 16B per lane; LDS dest = wave-uniform base + lane*16,
// global source is PER-LANE (enables token-indirect A staging)
static __device__ __forceinline__ void gl16(const void* g, void* l) {
  __builtin_amdgcn_global_load_lds(
      (const __attribute__((address_space(1))) unsigned int*)g,
      (__attribute__((address_space(3))) unsigned int*)l,
      16, 0, 0);
}

// ---------------- transpose + fp32->bf16, LDS-staged 128x128 tile (r13) ------
static __device__ __forceinline__ void transpose_body(const float* __restrict__ W,
                                                      unsigned short* __restrict__ WT,
                                                      int R, int C, int bx, int by, int e,
                                                      unsigned int* tl) {
  int t = threadIdx.x;
  int r0 = by * 128, c0 = bx * 128;
  const float* src = W + (size_t)e * R * C + (size_t)r0 * C + c0;
  int cg = t & 31, ph = t >> 5;                  // col-group (x4 floats), p-high
  int c4 = cg * 4;
#pragma unroll
  for (int u = 0; u < 8; ++u) {
    int p = u * 8 + ph;                          // row-pair 0..63
    float4 f0 = *(const float4*)(src + (size_t)(2 * p) * C + c4);
    float4 f1 = *(const float4*)(src + (size_t)(2 * p + 1) * C + c4);
    unsigned int v0 = ((unsigned)f2bf(f1.x) << 16) | f2bf(f0.x);
    unsigned int v1 = ((unsigned)f2bf(f1.y) << 16) | f2bf(f0.y);
    unsigned int v2 = ((unsigned)f2bf(f1.z) << 16) | f2bf(f0.z);
    unsigned int v3 = ((unsigned)f2bf(f1.w) << 16) | f2bf(f0.w);
    *(uint4*)(tl + p * 132 + c4) = make_uint4(v0, v1, v2, v3);
  }
  __syncthreads();
  int rg = t & 15, ch = t >> 4;                  // row-group (x8 rows), col-high
  unsigned short* dst = WT + (size_t)e * R * C + (size_t)c0 * R + r0 + rg * 8;
#pragma unroll
  for (int u = 0; u < 8; ++u) {
    int c = ch + u * 16;
    u16x8 o;
#pragma unroll
    for (int j = 0; j < 4; ++j) {
      unsigned int v = tl[(rg * 4 + j) * 132 + c];
      o[2 * j]     = (unsigned short)(v & 0xffff);
      o[2 * j + 1] = (unsigned short)(v >> 16);
    }
    *(u16x8*)(dst + (size_t)c * R) = o;
  }
}

static __device__ __forceinline__ void router_body(int blk, const float* __restrict__ x,
                                                   const float* __restrict__ Wr,
                                                   const float* __restrict__ br,
                                                   int* __restrict__ meta,
                                                   int2* __restrict__ top_i,
                                                   float2* __restrict__ top_w) {
  int lane = threadIdx.x & 63;
  int wid  = threadIdx.x >> 6;
  int t = blk * 4 + wid;
  const float* xp = x + (size_t)t * DIM + lane * 16;
  float acc[NEXP];
#pragma unroll
  for (int e = 0; e < NEXP; ++e) acc[e] = 0.f;
#pragma unroll
  for (int j = 0; j < 16; j += 4) {
    float4 xv = *(const float4*)(xp + j);
    const float* wp = Wr + (size_t)(lane * 16 + j) * NEXP;
#pragma unroll
    for (int jj = 0; jj < 4; ++jj) {
      float xs = jj == 0 ? xv.x : jj == 1 ? xv.y : jj == 2 ? xv.z : xv.w;
      float4 w0 = *(const float4*)(wp + jj * NEXP);
      float4 w1 = *(const float4*)(wp + jj * NEXP + 4);
      acc[0] += xs * w0.x; acc[1] += xs * w0.y; acc[2] += xs * w0.z; acc[3] += xs * w0.w;
      acc[4] += xs * w1.x; acc[5] += xs * w1.y; acc[6] += xs * w1.z; acc[7] += xs * w1.w;
    }
  }
#pragma unroll
  for (int off = 32; off > 0; off >>= 1) {
#pragma unroll
    for (int e = 0; e < NEXP; ++e) acc[e] += __shfl_xor(acc[e], off);
  }
  if (lane == 0) {
    float l[NEXP];
#pragma unroll
    for (int e = 0; e < NEXP; ++e) l[e] = acc[e] + br[e];
    int e1 = 0;
#pragma unroll
    for (int e = 1; e < NEXP; ++e) if (l[e] > l[e1]) e1 = e;      // ties -> lower idx
    int e2 = (e1 == 0) ? 1 : 0;
#pragma unroll
    for (int e = 0; e < NEXP; ++e) if (e != e1 && l[e] > l[e2]) e2 = e;
    float g  = expf(l[e2] - l[e1]);              // softmax over top-2 == renorm of full softmax
    float w1 = 1.f / (1.f + g);
    top_i[t] = make_int2(e1, e2);
    top_w[t] = make_float2(w1, 1.f - w1);
    atomicAdd(&meta[e1], 1);
    atomicAdd(&meta[e2], 1);
  }
}

// ---- fused prep: [0,2048) W1 transpose, [2048,4096) W2 transpose,
//      [4096,6144) router, [6144,6216) fill, [6216,8264) x->bf16 convert -----
__global__ __launch_bounds__(256) void prep_k(const float* __restrict__ W1,
                                              const float* __restrict__ W2,
                                              unsigned short* __restrict__ W1bT,
                                              unsigned short* __restrict__ W2bT,
                                              const float* __restrict__ x,
                                              const float* __restrict__ Wr,
                                              const float* __restrict__ br,
                                              int* __restrict__ meta,
                                              int2* __restrict__ top_i,
                                              float2* __restrict__ top_w,
                                              int* __restrict__ tok_of_row,
                                              float* __restrict__ wt_of_row,
                                              unsigned short* __restrict__ xb) {
  __shared__ __align__(16) unsigned int tl[64 * 132];   // 33792 B
  int id = blockIdx.x;
  if (id < 2048) {                               // W1[e][D][H] -> [e][H][D]
    int rem = id & 255;                          // 8 by x 32 bx per expert
    transpose_body(W1, W1bT, DIM, HID, rem & 31, rem >> 5, id >> 8, tl);
  } else if (id < 4096) {                        // W2[e][H][D] -> [e][D][H]
    int id2 = id - 2048;
    int rem = id2 & 255;                         // 32 by x 8 bx per expert
    transpose_body(W2, W2bT, HID, DIM, rem & 7, rem >> 3, id2 >> 8, tl);
  } else if (id < 6144) {
    router_body(id - 4096, x, Wr, br, meta, top_i, top_w);
  } else if (id < 6216) {
    int i = (id - 6144) * 256 + threadIdx.x;     // 72*256 == MAXR exactly
    if (i < MAXR) { tok_of_row[i] = 0; wt_of_row[i] = 0.f; }
  } else {                                       // xb = bf16(x), streaming
    size_t o = (size_t)(id - 6216) * 4096 + (size_t)threadIdx.x * 16;
#pragma unroll
    for (int h = 0; h < 2; ++h) {
      float4 a = *(const float4*)(x + o + h * 8);
      float4 b = *(const float4*)(x + o + h * 8 + 4);
      u16x8 v;
      v[0] = f2bf(a.x); v[1] = f2bf(a.y); v[2] = f2bf(a.z); v[3] = f2bf(a.w);
      v[4] = f2bf(b.x); v[5] = f2bf(b.y); v[6] = f2bf(b.z); v[7] = f2bf(b.w);
      *(u16x8*)(xb + o + h * 8) = v;
    }
  }
}

// -------- prefix: padded (x256) offsets ------------------------------------
__global__ void prefix_k(int* __restrict__ meta) {
  if (threadIdx.x == 0) {
    int s = 0;
#pragma unroll
    for (int e = 0; e < NEXP; ++e) {
      meta[16 + e] = s;                          // poff[e]
      s += (meta[e] + 255) & ~255;
    }
    meta[24] = s;                                // poff[8]
    meta[25] = s;                                // total_padded (<= MAXR always)
  }
}

// ---------------- scatter: token -> packed expert row ------------------------
__global__ __launch_bounds__(256) void scatter_k(const int2* __restrict__ top_i,
                                                 const float2* __restrict__ top_w,
                                                 int* __restrict__ meta,
                                                 int* __restrict__ row_of,
                                                 int* __restrict__ tok_of_row,
                                                 float* __restrict__ wt_of_row) {
  int t = blockIdx.x * 256 + threadIdx.x;
  int2  ei = top_i[t];
  float2 w = top_w[t];
  int p = atomicAdd(&meta[8 + ei.x], 1);
  int r = meta[16 + ei.x] + p;
  tok_of_row[r] = t; wt_of_row[r] = w.x; row_of[t * 2] = r;
  p = atomicAdd(&meta[8 + ei.y], 1);
  r = meta[16 + ei.y] + p;
  tok_of_row[r] = t; wt_of_row[r] = w.y; row_of[t * 2 + 1] = r;
}

// ---------------- grouped GEMM: r13 loop; A optionally token-indirect --------
// INDIR=1 (GEMM1): A = xb[T][KTOT], A-row for packed row r is xb[tok_of_row[r]]
//   via per-lane gl16 source addresses (4 statically-unrolled base pointers).
// INDIR=0 (GEMM2): A = packed hbuf rows (as r13).
// 128x128 tile, BK=64, 4 waves, 32KB LDS, [128 rows][8 slots x 8] XOR swizzle,
// XCD-chunked 4x4 supertiles, pad-tile skip.
// EPI 0: h = bf16(gelu(acc+b1))   EPI 1: atomicAdd out[tok] += (acc+b2)*wt

template <int KTOT, int NTOT, int EPI, bool INDIR>
__global__ __launch_bounds__(256, 4) void gemmv16_k(const unsigned short* __restrict__ A,
                                                    const unsigned short* __restrict__ Bt,
                                                    const float* __restrict__ bias,
                                                    const int* __restrict__ meta,
                                                    const float* __restrict__ wt_of_row,
                                                    const int* __restrict__ tok_of_row,
                                                    void* __restrict__ Cout) {
  constexpr int NN  = NTOT / 128;                // 32 or 8
  constexpr int NXB = MAXR / 128;                // 144 row tiles
  constexpr int NWG = NXB * NN;                  // 4608 or 1152, both % 8 == 0
  constexpr int NSR = NXB / 4;                   // 36 row supertiles
  constexpr int NKT = KTOT / 64;                 // 16 or 64
  __shared__ __align__(16) unsigned short lds[16384];   // 32 KiB

  int id = ((int)blockIdx.x & 7) * (NWG / 8) + ((int)blockIdx.x >> 3);
  int sid = id >> 4, sub = id & 15;
  int row0 = ((sid % NSR) * 4 + (sub & 3)) * 128;
  int n0   = ((sid / NSR) * 4 + (sub >> 2)) * 128;
  if (row0 >= meta[25]) return;                  // beyond padded total (block-uniform)
  int e = 0;
  while (meta[17 + e] <= row0) ++e;              // tiles never straddle experts
  if (row0 - meta[16 + e] >= meta[e]) return;    // all-pad tile: skip (wt==0 gates EPI1)
  const unsigned short* Bp = Bt + (size_t)e * NTOT * KTOT;

  int tid = threadIdx.x;
  int lane = tid & 63, wid = tid >> 6;
  int wm = wid >> 1, wn = wid & 1;               // 2x2 waves, each owns 64x64 of C

  // staging (T2 write side): source col-slot s = (tid&7) ^ ((tid>>3)&7)
  int s = (tid & 7) ^ ((tid >> 3) & 7);
  const unsigned short* pA[4];
#pragma unroll
  for (int i = 0; i < 4; ++i) {
    int r = row0 + (tid >> 3) + i * 32;
    if constexpr (INDIR) {
      pA[i] = A + (size_t)tok_of_row[r] * KTOT + s * 8;   // pad rows: tok 0 (valid)
    } else {
      pA[i] = A + (size_t)r * KTOT + s * 8;
    }
  }
  const unsigned short* pB = Bp + (size_t)(n0 + (tid >> 3)) * KTOT + s * 8;

  // fragment reads (T2 read side): slot = (kk*4+g) ^ (am&7)
  int am = lane & 15, g = lane >> 4;
  int sw0 = ((0 * 4 + g) ^ (am & 7)) * 8;
  int sw1 = ((1 * 4 + g) ^ (am & 7)) * 8;
  int aRow = (wm * 64 + am) * 64;                // + i*1024 per fragment
  int bRow = 8192 + (wn * 64 + am) * 64;         // + j*1024 per fragment

  f32x4 acc[4][4];
#pragma unroll
  for (int i = 0; i < 4; ++i)
#pragma unroll
    for (int j = 0; j < 4; ++j) acc[i][j] = (f32x4){0.f, 0.f, 0.f, 0.f};

  for (int kt = 0; kt < NKT; ++kt) {
    __syncthreads();                             // prev compute done before overwrite
#pragma unroll
    for (int i = 0; i < 4; ++i) {
      gl16(pA[i] + kt * 64, lds + i * 2048 + tid * 8);
      gl16(pB + (size_t)(i * 32) * KTOT + kt * 64, lds + 8192 + i * 2048 + tid * 8);
    }
    __syncthreads();                             // compiler drains vmcnt before barrier
#pragma unroll
    for (int kk = 0; kk < 2; ++kk) {
      int sw = kk ? sw1 : sw0;
      bf16x8 af[4], bv[4];
#pragma unroll
      for (int i = 0; i < 4; ++i)
        af[i] = *(const bf16x8*)(lds + aRow + i * 1024 + sw);
#pragma unroll
      for (int j = 0; j < 4; ++j)
        bv[j] = *(const bf16x8*)(lds + bRow + j * 1024 + sw);
#pragma unroll
      for (int i = 0; i < 4; ++i)
#pragma unroll
        for (int j = 0; j < 4; ++j)
          acc[i][j] = __builtin_amdgcn_mfma_f32_16x16x32_bf16(af[i], bv[j], acc[i][j], 0, 0, 0);
    }
  }

  // epilogue.  C/D: col n = lane&15, row m = (lane>>4)*4 + reg  (validated)
  int rbase = row0 + wm * 64 + (g << 2);
  int nbase = n0 + wn * 64 + am;
  if constexpr (EPI == 0) {
    unsigned short* Hp = (unsigned short*)Cout;
    const float* bp = bias + (size_t)e * NTOT;
#pragma unroll
    for (int i = 0; i < 4; ++i)
#pragma unroll
      for (int j = 0; j < 4; ++j) {
        int n = nbase + j * 16;
        float bv = bp[n];
#pragma unroll
        for (int gg = 0; gg < 4; ++gg) {
          int m = rbase + i * 16 + gg;
          float v = acc[i][j][gg] + bv;
          v = 0.5f * v * (1.f + erff(v * 0.70710678118654752f));   // exact gelu
          Hp[(size_t)m * NTOT + n] = f2bf(v);
        }
      }
  } else {
    float* Op = (float*)Cout;
    const float* bp = bias + (size_t)e * NTOT;
#pragma unroll
    for (int i = 0; i < 4; ++i)
#pragma unroll
      for (int gg = 0; gg < 4; ++gg) {
        int m = rbase + i * 16 + gg;
        float wt = wt_of_row[m];
        if (wt != 0.f) {                         // pad rows excluded (wt exactly 0)
          float* orow = Op + (size_t)tok_of_row[m] * DIM;
#pragma unroll
          for (int j = 0; j < 4; ++j) {
            int n = nbase + j * 16;
            atomicAdd(orow + n, (acc[i][j][gg] + bp[n]) * wt);
          }
        }
      }
  }
}

extern "C" void kernel_launch(void* const* d_in, const int* in_sizes, int n_in,
                              void* d_out, int out_size, void* d_ws, size_t ws_size,
                              hipStream_t stream) {
  const float* x  = (const float*)d_in[0];
  const float* Wr = (const float*)d_in[1];
  const float* br = (const float*)d_in[2];
  const float* W1 = (const float*)d_in[3];
  const float* b1 = (const float*)d_in[4];
  const float* W2 = (const float*)d_in[5];
  const float* b2 = (const float*)d_in[6];
  float* out = (float*)d_out;

  char* base = (char*)d_ws;
  size_t off = 0;
  auto carve = [&](size_t bytes) -> void* {
    void* r = base + off;
    off = (off + bytes + 255) & ~(size_t)255;
    return r;
  };
  int*            meta       = (int*)carve(26 * 4);
  int2*           top_i      = (int2*)carve((size_t)T_TOK * 8);
  float2*         top_w      = (float2*)carve((size_t)T_TOK * 8);
  int*            row_of     = (int*)carve((size_t)T_TOK * 2 * 4);
  int*            tok_of_row = (int*)carve((size_t)MAXR * 4);
  float*          wt_of_row  = (float*)carve((size_t)MAXR * 4);
  unsigned short* xb         = (unsigned short*)carve((size_t)T_TOK * DIM * 2);
  unsigned short* W1bT       = (unsigned short*)carve((size_t)NEXP * DIM * HID * 2);
  unsigned short* W2bT       = (unsigned short*)carve((size_t)NEXP * DIM * HID * 2);
  unsigned short* hbuf       = (unsigned short*)carve((size_t)MAXR * HID * 2);
  if (off > ws_size) {
    fprintf(stderr, "kernel_launch: ws_size too small: need %zu have %zu\n", off, ws_size);
    return;
  }

  hipMemsetAsync(meta, 0, 26 * 4, stream);
  hipMemsetAsync(out, 0, (size_t)out_size * 4, stream);   // GEMM2 atomicAdds into out
  hipLaunchKernelGGL(prep_k, dim3(8264), dim3(256), 0, stream,
                     W1, W2, W1bT, W2bT, x, Wr, br, meta, top_i, top_w,
                     tok_of_row, wt_of_row, xb);
  hipLaunchKernelGGL(prefix_k, dim3(1), dim3(64), 0, stream, meta);
  hipLaunchKernelGGL(scatter_k, dim3(T_TOK / 256), dim3(256), 0, stream,
                     top_i, top_w, meta, row_of, tok_of_row, wt_of_row);
  hipLaunchKernelGGL((gemmv16_k<DIM, HID, 0, true>), dim3((MAXR / 128) * (HID / 128)),
                     dim3(256), 0, stream,
                     xb, W1bT, b1, meta, wt_of_row, tok_of_row, (void*)hbuf);
  hipLaunchKernelGGL((gemmv16_k<HID, DIM, 1, false>), dim3((MAXR / 128) * (DIM / 128)),
                     dim3(256), 0, stream,
                     hbuf, W2bT, b2, meta, wt_of_row, tok_of_row, (void*)out);
}